// Round 5
// baseline (68.791 us; speedup 1.0000x reference)
//
#include <hip/hip_runtime.h>
#include <math.h>

#define T 34
#define V 14
#define NT 256
#define NBLK 2176
#define NWAVES 8704            // NBLK * 4 waves
#define KTILES 4               // tiles per wave; NWAVES*KTILES*64 = 65536*34
#define LIM (65536 * 34)

__global__ __launch_bounds__(NT, 4) void micro_main(
    const int* __restrict__ idx, float* __restrict__ out,
    const float* __restrict__ p_tokA, const float* __restrict__ p_tokStart,
    const float* __restrict__ p_tokStride, const float* __restrict__ p_spAmp,
    const float* __restrict__ p_spPhase, const float* __restrict__ p_spSlope,
    const float* __restrict__ p_spOffset, const float* __restrict__ norm_w,
    const float* __restrict__ q_w, const float* __restrict__ q_phase,
    const float* __restrict__ out_A, const float* __restrict__ out_B,
    const float* __restrict__ fc1_w, const float* __restrict__ fc2_w,
    const float* __restrict__ head_w)
{
    __shared__ float G_lds[V * 35];      // g(v,s), padded rows of 35
    __shared__ float TE_lds[V * 2];
    __shared__ float POS_lds[T][3];
    __shared__ float gbW[4][104];        // per-warp staged g
    __shared__ float stageAll[4 * 896];  // logit staging; doubles as setup scratch

    const int tid = threadIdx.x;
    const int w = tid >> 6, lane = tid & 63;
    const int wid = blockIdx.x * 4 + w;

    // ---------------- per-block parallel setup (3 barriers total) ----------------
    float* sA  = stageAll;               // A_pad[34][35] during setup
    float* sKp = stageAll + 1200;        // K[34][5]
    float* sQp = stageAll + 1400;        // Q[34][5]

    if (tid < V) {
        float ang = p_tokStart[0] + (float)tid * p_tokStride[0];
        TE_lds[2 * tid]     = p_tokA[0] * cosf(ang);
        TE_lds[2 * tid + 1] = p_tokA[0] * sinf(ang);
    }
    if (tid < T) {
        float th = (float)tid * 0.62831853071795864769f + p_spPhase[0]; // 2*pi/10
        float p0 = p_spAmp[0] * cosf(th), p1 = p_spAmp[0] * sinf(th);
        float p2 = p_spSlope[0] * (float)tid + p_spOffset[0];
        POS_lds[tid][0] = p0; POS_lds[tid][1] = p1; POS_lds[tid][2] = p2;
        float kk[5];
        #pragma unroll
        for (int i = 0; i < 5; ++i)
            kk[i] = p0 * q_w[3 * i] + p1 * q_w[3 * i + 1] + p2 * q_w[3 * i + 2];
        float cc = cosf(q_phase[0]), ss = sinf(q_phase[0]);
        #pragma unroll
        for (int i = 0; i < 5; ++i) sKp[tid * 5 + i] = kk[i];
        sQp[tid * 5 + 0] = cc * kk[0] - ss * kk[1];
        sQp[tid * 5 + 1] = ss * kk[0] + cc * kk[1];
        sQp[tid * 5 + 2] = kk[2]; sQp[tid * 5 + 3] = kk[3]; sQp[tid * 5 + 4] = kk[4];
    }
    __syncthreads();

    if (tid < T) {
        const int t = tid;
        float q0 = sQp[t*5], q1 = sQp[t*5+1], q2 = sQp[t*5+2], q3 = sQp[t*5+3], q4 = sQp[t*5+4];
        float sc[T];
        float mx = -1e30f;
        for (int s = 0; s <= t; ++s) {
            float d = (q0 * sKp[s*5] + q1 * sKp[s*5+1] + q2 * sKp[s*5+2]
                     + q3 * sKp[s*5+3] + q4 * sKp[s*5+4]) * 0.44721359549995793928f;
            sc[s] = d;
            mx = fmaxf(mx, d);
        }
        float sum = 0.f;
        for (int s = 0; s <= t; ++s) { float e = expf(sc[s] - mx); sc[s] = e; sum += e; }
        float inv = 1.f / sum;
        for (int s = 0; s < 35; ++s) sA[t * 35 + s] = (s <= t && s < T) ? sc[s] * inv : 0.f;
    }
    for (int e = tid; e < V * 35; e += NT) {
        int v = e / 35, s = e - v * 35;
        float g = 0.f;
        if (s < T) {
            float x0 = TE_lds[2*v], x1 = TE_lds[2*v+1];
            float x2 = POS_lds[s][0], x3 = POS_lds[s][1], x4 = POS_lds[s][2];
            float ms = (x0*x0 + x1*x1 + x2*x2 + x3*x3 + x4*x4) * 0.2f;
            float r = rsqrtf(ms + 1e-5f);
            g = (x0 * norm_w[0] * out_A[0] + x1 * norm_w[1] * out_A[1]
               + x2 * norm_w[2] * out_A[2] + x3 * norm_w[3] * out_A[3]
               + x4 * norm_w[4] * out_A[4]) * r;
        }
        G_lds[e] = g;
    }
    __syncthreads();

    // ---------------- per-wave invariants ----------------
    const int t = (wid * 64 + lane) % T;   // invariant across this wave's tiles
    float A[T];
    #pragma unroll
    for (int s = 0; s < T; ++s) A[s] = sA[t * 35 + s];
    const float ps0 = POS_lds[t][0], ps1 = POS_lds[t][1], ps2 = POS_lds[t][2];
    __syncthreads();   // A reads complete; stageAll reusable as logit stage

    // uniform weights (literal-indexed -> scalar loads / SGPRs)
    const float nw0 = norm_w[0], nw1 = norm_w[1], nw2 = norm_w[2], nw3 = norm_w[3], nw4 = norm_w[4];
    const float oB0 = out_B[0], oB1 = out_B[1], oB2 = out_B[2], oB3 = out_B[3], oB4 = out_B[4];
    float w1[2][5], hw[2][5], w20[5], w21[5];
    #pragma unroll
    for (int j = 0; j < 2; ++j)
        #pragma unroll
        for (int d = 0; d < 5; ++d) { w1[j][d] = fc1_w[j*5+d]; hw[j][d] = head_w[j*5+d]; }
    #pragma unroll
    for (int d = 0; d < 5; ++d) { w20[d] = fc2_w[2*d]; w21[d] = fc2_w[2*d+1]; }
    float te0[V], te1[V];
    #pragma unroll
    for (int v = 0; v < V; ++v) { te0[v] = TE_lds[2*v]; te1[v] = TE_lds[2*v+1]; }

    // per-lane invariants for the 102-value g staging
    const int s_a = (lane < T) ? lane : lane - T;
    const int i2 = lane + 64;
    const int s_b = (i2 < 68) ? i2 - 34 : i2 - 68;
    const bool act2 = (i2 < 102);

    float* gb = gbW[w];
    float* stg = stageAll + w * 896;
    float2* stg2 = reinterpret_cast<float2*>(stg);
    const float4* st4 = reinterpret_cast<const float4*>(stg);

    int tile = wid;
    int b0 = (tile * 64) / T;
    int tk0 = idx[b0 * T + lane];                       // always in range
    int tk1 = idx[min(b0 * T + lane + 64, LIM - 1)];    // clamp (value unused when OOB)
    int tko = idx[tile * 64 + lane];                    // this lane's own token

    #pragma unroll
    for (int k = 0; k < KTILES; ++k) {
        // ---- warp-local g staging (same-wave LDS ops in order; compiler waits) ----
        gb[lane] = G_lds[tk0 * 35 + s_a];
        if (act2) gb[i2] = G_lds[tk1 * 35 + s_b];

        const int item = tile * 64 + lane;
        const int b = item / T;
        const int rbase = (b - b0) * T;
        const int curtok = tko;
        const int tile_n = tile + NWAVES;

        // ---- prefetch next tile's tokens ----
        if (k < KTILES - 1) {
            int b0n = (tile_n * 64) / T;
            tk0 = idx[b0n * T + lane];
            tk1 = idx[min(b0n * T + lane + 64, LIM - 1)];
            tko = idx[tile_n * 64 + lane];
            b0 = b0n;
        }

        // ---- attention dot: A-column (regs) . g-row (LDS, broadcast-friendly) ----
        float acc = 0.f;
        const float2* gbp = reinterpret_cast<const float2*>(gb + rbase);
        #pragma unroll
        for (int s = 0; s < 17; ++s) {
            float2 gg = gbp[s];
            acc = fmaf(A[2*s], gg.x, acc);
            acc = fmaf(A[2*s+1], gg.y, acc);
        }

        float2 te = *reinterpret_cast<const float2*>(&TE_lds[curtok * 2]);
        float x0 = te.x + acc * oB0;
        float x1 = te.y + acc * oB1;
        float x2 = ps0 + acc * oB2;
        float x3 = ps1 + acc * oB3;
        float x4 = ps2 + acc * oB4;

        // FFN (pre-norm)
        float ms = (x0*x0 + x1*x1 + x2*x2 + x3*x3 + x4*x4) * 0.2f;
        float rr = rsqrtf(ms + 1e-5f);
        float h0 = x0*rr*nw0, h1 = x1*rr*nw1, h2 = x2*rr*nw2, h3 = x3*rr*nw3, h4 = x4*rr*nw4;
        float f0 = fmaxf(0.f, h0*w1[0][0] + h1*w1[0][1] + h2*w1[0][2] + h3*w1[0][3] + h4*w1[0][4]);
        float f1 = fmaxf(0.f, h0*w1[1][0] + h1*w1[1][1] + h2*w1[1][2] + h3*w1[1][3] + h4*w1[1][4]);
        x0 += f0*w20[0] + f1*w21[0];
        x1 += f0*w20[1] + f1*w21[1];
        x2 += f0*w20[2] + f1*w21[2];
        x3 += f0*w20[3] + f1*w21[3];
        x4 += f0*w20[4] + f1*w21[4];

        // head (pre-norm)
        ms = (x0*x0 + x1*x1 + x2*x2 + x3*x3 + x4*x4) * 0.2f;
        rr = rsqrtf(ms + 1e-5f);
        h0 = x0*rr*nw0; h1 = x1*rr*nw1; h2 = x2*rr*nw2; h3 = x3*rr*nw3; h4 = x4*rr*nw4;
        float p0 = h0*hw[0][0] + h1*hw[0][1] + h2*hw[0][2] + h3*hw[0][3] + h4*hw[0][4];
        float p1 = h0*hw[1][0] + h1*hw[1][1] + h2*hw[1][2] + h3*hw[1][3] + h4*hw[1][4];

        // ---- logits -> warp-local stage (7 x ds_write_b64) ----
        #pragma unroll
        for (int j = 0; j < 7; ++j) {
            float2 o2;
            o2.x = p0 * te0[2*j]   + p1 * te1[2*j];
            o2.y = p0 * te0[2*j+1] + p1 * te1[2*j+1];
            stg2[lane * 7 + j] = o2;
        }

        // ---- coalesced copyout: 3584 B contiguous per tile, fire-and-forget ----
        float4* outp = reinterpret_cast<float4*>(out) + (size_t)tile * 224;
        outp[lane]       = st4[lane];
        outp[lane + 64]  = st4[lane + 64];
        outp[lane + 128] = st4[lane + 128];
        if (lane < 32) outp[lane + 192] = st4[lane + 192];

        tile = tile_n;
    }
}

extern "C" void kernel_launch(void* const* d_in, const int* in_sizes, int n_in,
                              void* d_out, int out_size, void* d_ws, size_t ws_size,
                              hipStream_t stream) {
    const int*   idx        = (const int*)  d_in[0];
    const float* tok_A      = (const float*)d_in[1];
    const float* tok_start  = (const float*)d_in[2];
    const float* tok_stride = (const float*)d_in[3];
    const float* sp_amp     = (const float*)d_in[4];
    const float* sp_phase   = (const float*)d_in[5];
    const float* sp_slope   = (const float*)d_in[6];
    const float* sp_offset  = (const float*)d_in[7];
    const float* norm_w     = (const float*)d_in[8];
    const float* q_w        = (const float*)d_in[9];
    const float* q_phase    = (const float*)d_in[10];
    const float* out_A      = (const float*)d_in[11];
    const float* out_B      = (const float*)d_in[12];
    const float* fc1_w      = (const float*)d_in[13];
    const float* fc2_w      = (const float*)d_in[14];
    const float* head_w     = (const float*)d_in[15];
    float* out = (float*)d_out;

    micro_main<<<NBLK, NT, 0, stream>>>(idx, out, tok_A, tok_start, tok_stride,
                                        sp_amp, sp_phase, sp_slope, sp_offset,
                                        norm_w, q_w, q_phase, out_A, out_B,
                                        fc1_w, fc2_w, head_w);
}

// Round 6
// 39.568 us; speedup vs baseline: 1.7386x; 1.7386x over previous
//
#include <hip/hip_runtime.h>
#include <math.h>

#define T 34
#define V 14
#define NT 256
#define NBLK 2176
#define NWAVES 8704            // NBLK * 4 waves
#define LIM (65536 * 34)

typedef float f32x4 __attribute__((ext_vector_type(4)));

// d_ws float layout:
//   [0 .. 1190)      A_pad[34][35]  softmaxed causal attn, row t, 0 for s>t
//   [1190 .. 1680)   G_pad[14][35]  g(v,s) = rmsnorm(x(v,s)) . out_A
//   [1680 .. 1708)   TE[14][2]
//   [1708 .. 1810)   POS[34][3]

__global__ void setup_k(const float* __restrict__ tokA_p, const float* __restrict__ tokStart_p,
                        const float* __restrict__ tokStride_p, const float* __restrict__ spAmp_p,
                        const float* __restrict__ spPhase_p, const float* __restrict__ spSlope_p,
                        const float* __restrict__ spOffset_p, const float* __restrict__ norm_w,
                        const float* __restrict__ q_w, const float* __restrict__ q_phase,
                        const float* __restrict__ out_A, float* __restrict__ ws)
{
    __shared__ float sPOS[T][3];
    __shared__ float sK[T][5];
    __shared__ float sQ[T][5];
    __shared__ float sTE[V][2];
    __shared__ float sA[T][35];

    const int tid = threadIdx.x;   // 64 threads, 1 block

    if (tid < V) {
        float ang = tokStart_p[0] + (float)tid * tokStride_p[0];
        float c = tokA_p[0] * cosf(ang), s = tokA_p[0] * sinf(ang);
        sTE[tid][0] = c; sTE[tid][1] = s;
        ws[1680 + 2 * tid] = c; ws[1681 + 2 * tid] = s;
    }
    if (tid < T) {
        float th = (float)tid * 0.62831853071795864769f + spPhase_p[0];
        float p0 = spAmp_p[0] * cosf(th), p1 = spAmp_p[0] * sinf(th);
        float p2 = spSlope_p[0] * (float)tid + spOffset_p[0];
        sPOS[tid][0] = p0; sPOS[tid][1] = p1; sPOS[tid][2] = p2;
        ws[1708 + 3 * tid] = p0; ws[1709 + 3 * tid] = p1; ws[1710 + 3 * tid] = p2;
        float kk[5];
        #pragma unroll
        for (int i = 0; i < 5; ++i)
            kk[i] = p0 * q_w[3 * i] + p1 * q_w[3 * i + 1] + p2 * q_w[3 * i + 2];
        float cc = cosf(q_phase[0]), ss = sinf(q_phase[0]);
        #pragma unroll
        for (int i = 0; i < 5; ++i) sK[tid][i] = kk[i];
        sQ[tid][0] = cc * kk[0] - ss * kk[1];
        sQ[tid][1] = ss * kk[0] + cc * kk[1];
        sQ[tid][2] = kk[2]; sQ[tid][3] = kk[3]; sQ[tid][4] = kk[4];
    }
    __syncthreads();

    if (tid < T) {
        const int t = tid;
        float mx = -1e30f;
        for (int s = 0; s <= t; ++s) {
            float d = (sQ[t][0] * sK[s][0] + sQ[t][1] * sK[s][1] + sQ[t][2] * sK[s][2]
                     + sQ[t][3] * sK[s][3] + sQ[t][4] * sK[s][4]) * 0.44721359549995793928f;
            sA[t][s] = d;
            mx = fmaxf(mx, d);
        }
        float sum = 0.f;
        for (int s = 0; s <= t; ++s) { float e = expf(sA[t][s] - mx); sA[t][s] = e; sum += e; }
        float inv = 1.f / sum;
        for (int s = 0; s < 35; ++s) ws[t * 35 + s] = (s <= t) ? sA[t][s] * inv : 0.f;
    }
    for (int e = tid; e < 490; e += 64) {
        int v = e / 35, s = e - v * 35;
        float g = 0.f;
        if (s < T) {
            float x0 = sTE[v][0], x1 = sTE[v][1];
            float x2 = sPOS[s][0], x3 = sPOS[s][1], x4 = sPOS[s][2];
            float ms = (x0*x0 + x1*x1 + x2*x2 + x3*x3 + x4*x4) * 0.2f;
            float r = rsqrtf(ms + 1e-5f);
            g = (x0 * norm_w[0] * out_A[0] + x1 * norm_w[1] * out_A[1]
               + x2 * norm_w[2] * out_A[2] + x3 * norm_w[3] * out_A[3]
               + x4 * norm_w[4] * out_A[4]) * r;
        }
        ws[1190 + e] = g;
    }
}

__global__ __launch_bounds__(NT, 4) void micro_main(
    const int* __restrict__ idx, const float* __restrict__ ws, float* __restrict__ out,
    const float* __restrict__ norm_w, const float* __restrict__ out_B,
    const float* __restrict__ fc1_w, const float* __restrict__ fc2_w,
    const float* __restrict__ head_w)
{
    __shared__ float G_lds[V * 35];      // 1960 B (never written after init)
    __shared__ float TE_lds[V * 2];      // 112 B
    __shared__ float gbW[4][2][104];     // per-wave, per-tile staged g (3328 B)
    __shared__ float stageAll[4 * 896];  // per-wave logit staging (14336 B)
    // total ~19.7 KB -> 8 blocks/CU LDS-limit

    const int tid = threadIdx.x;
    const int w = tid >> 6, lane = tid & 63;
    const int wid = blockIdx.x * 4 + w;

    // ---- one-time table load: the ONLY barrier in this kernel ----
    for (int i = tid; i < 490; i += NT) G_lds[i] = ws[1190 + i];
    if (tid < 28) TE_lds[tid] = ws[1680 + tid];
    __syncthreads();

    // ---- per-lane invariants ----
    const int t = (wid * 64 + lane) % T;   // invariant across this wave's tiles
    float A[T];
    #pragma unroll
    for (int s = 0; s < T; ++s) A[s] = ws[t * 35 + s];   // global, one-time, -> VGPRs
    const float ps0 = ws[1708 + 3 * t], ps1 = ws[1709 + 3 * t], ps2 = ws[1710 + 3 * t];

    // uniform weights: literal-indexed -> s_load -> SGPRs
    const float nw0 = norm_w[0], nw1 = norm_w[1], nw2 = norm_w[2], nw3 = norm_w[3], nw4 = norm_w[4];
    const float oB0 = out_B[0], oB1 = out_B[1], oB2 = out_B[2], oB3 = out_B[3], oB4 = out_B[4];
    float w1[2][5], hw[2][5], w20[5], w21[5];
    #pragma unroll
    for (int j = 0; j < 2; ++j)
        #pragma unroll
        for (int d = 0; d < 5; ++d) { w1[j][d] = fc1_w[j*5+d]; hw[j][d] = head_w[j*5+d]; }
    #pragma unroll
    for (int d = 0; d < 5; ++d) { w20[d] = fc2_w[2*d]; w21[d] = fc2_w[2*d+1]; }
    float te0[V], te1[V];
    #pragma unroll
    for (int v = 0; v < V; ++v) { te0[v] = ws[1680 + 2*v]; te1[v] = ws[1681 + 2*v]; }

    // staging-lane invariants
    const int s_a = (lane < T) ? lane : lane - T;
    const int i2 = lane + 64;
    const int s_b = (i2 < 68) ? i2 - 34 : i2 - 68;
    const bool act2 = (i2 < 102);

    float* gbA = gbW[w][0];
    float* gbB = gbW[w][1];
    float* stg = stageAll + w * 896;
    float2* stg2 = reinterpret_cast<float2*>(stg);
    const f32x4* st4 = reinterpret_cast<const f32x4*>(stg);

    // full item pipeline for one tile (dot -> epilogue -> logits -> copyout)
    auto computeItem = [&](int tile, int rbase, int curtok, const float* gbT) {
        float acc0 = 0.f, acc1 = 0.f;
        const float2* gbp = reinterpret_cast<const float2*>(gbT + rbase);
        #pragma unroll
        for (int s = 0; s < 17; ++s) {
            float2 gg = gbp[s];
            acc0 = fmaf(A[2*s],   gg.x, acc0);
            acc1 = fmaf(A[2*s+1], gg.y, acc1);
        }
        float acc = acc0 + acc1;

        float2 te = *reinterpret_cast<const float2*>(&TE_lds[curtok * 2]);
        float x0 = te.x + acc * oB0;
        float x1 = te.y + acc * oB1;
        float x2 = ps0 + acc * oB2;
        float x3 = ps1 + acc * oB3;
        float x4 = ps2 + acc * oB4;

        float ms = (x0*x0 + x1*x1 + x2*x2 + x3*x3 + x4*x4) * 0.2f;
        float rr = rsqrtf(ms + 1e-5f);
        float h0 = x0*rr*nw0, h1 = x1*rr*nw1, h2 = x2*rr*nw2, h3 = x3*rr*nw3, h4 = x4*rr*nw4;
        float f0 = fmaxf(0.f, h0*w1[0][0] + h1*w1[0][1] + h2*w1[0][2] + h3*w1[0][3] + h4*w1[0][4]);
        float f1 = fmaxf(0.f, h0*w1[1][0] + h1*w1[1][1] + h2*w1[1][2] + h3*w1[1][3] + h4*w1[1][4]);
        x0 += f0*w20[0] + f1*w21[0];
        x1 += f0*w20[1] + f1*w21[1];
        x2 += f0*w20[2] + f1*w21[2];
        x3 += f0*w20[3] + f1*w21[3];
        x4 += f0*w20[4] + f1*w21[4];

        ms = (x0*x0 + x1*x1 + x2*x2 + x3*x3 + x4*x4) * 0.2f;
        rr = rsqrtf(ms + 1e-5f);
        h0 = x0*rr*nw0; h1 = x1*rr*nw1; h2 = x2*rr*nw2; h3 = x3*rr*nw3; h4 = x4*rr*nw4;
        float p0 = h0*hw[0][0] + h1*hw[0][1] + h2*hw[0][2] + h3*hw[0][3] + h4*hw[0][4];
        float p1 = h0*hw[1][0] + h1*hw[1][1] + h2*hw[1][2] + h3*hw[1][3] + h4*hw[1][4];

        #pragma unroll
        for (int j = 0; j < 7; ++j) {
            float2 o2;
            o2.x = p0 * te0[2*j]   + p1 * te1[2*j];
            o2.y = p0 * te0[2*j+1] + p1 * te1[2*j+1];
            stg2[lane * 7 + j] = o2;
        }
        // same-wave LDS ordering: reads below see the writes above
        f32x4* outp = reinterpret_cast<f32x4*>(out) + (size_t)tile * 224;
        __builtin_nontemporal_store(st4[lane],       outp + lane);
        __builtin_nontemporal_store(st4[lane + 64],  outp + lane + 64);
        __builtin_nontemporal_store(st4[lane + 128], outp + lane + 128);
        if (lane < 32)
            __builtin_nontemporal_store(st4[lane + 192], outp + lane + 192);
    };

    // ---- 4 tiles per wave, processed as 2 pairs (2-way ILP) ----
    int tileA = wid, tileB = wid + NWAVES;
    int b0A = (tileA * 64) / T, b0B = (tileB * 64) / T;
    int tk0A = idx[b0A * T + lane];
    int tk1A = idx[min(b0A * T + lane + 64, LIM - 1)];
    int tkoA = idx[tileA * 64 + lane];
    int tk0B = idx[b0B * T + lane];
    int tk1B = idx[min(b0B * T + lane + 64, LIM - 1)];
    int tkoB = idx[tileB * 64 + lane];

    #pragma unroll
    for (int it = 0; it < 2; ++it) {
        // stage both tiles' g rows
        gbA[lane] = G_lds[tk0A * 35 + s_a];
        if (act2) gbA[i2] = G_lds[tk1A * 35 + s_b];
        gbB[lane] = G_lds[tk0B * 35 + s_a];
        if (act2) gbB[i2] = G_lds[tk1B * 35 + s_b];

        const int rbA = ((tileA * 64 + lane) / T - b0A) * T;
        const int rbB = ((tileB * 64 + lane) / T - b0B) * T;
        const int ctA = tkoA, ctB = tkoB;
        const int tA = tileA, tB = tileB;

        // prefetch next pair's tokens (hidden under this pair's compute)
        if (it == 0) {
            tileA += 2 * NWAVES; tileB += 2 * NWAVES;
            b0A = (tileA * 64) / T; b0B = (tileB * 64) / T;
            tk0A = idx[b0A * T + lane];
            tk1A = idx[min(b0A * T + lane + 64, LIM - 1)];
            tkoA = idx[tileA * 64 + lane];
            tk0B = idx[b0B * T + lane];
            tk1B = idx[min(b0B * T + lane + 64, LIM - 1)];
            tkoB = idx[tileB * 64 + lane];
        }

        computeItem(tA, rbA, ctA, gbA);
        computeItem(tB, rbB, ctB, gbB);
    }
}

extern "C" void kernel_launch(void* const* d_in, const int* in_sizes, int n_in,
                              void* d_out, int out_size, void* d_ws, size_t ws_size,
                              hipStream_t stream) {
    const int*   idx        = (const int*)  d_in[0];
    const float* tok_A      = (const float*)d_in[1];
    const float* tok_start  = (const float*)d_in[2];
    const float* tok_stride = (const float*)d_in[3];
    const float* sp_amp     = (const float*)d_in[4];
    const float* sp_phase   = (const float*)d_in[5];
    const float* sp_slope   = (const float*)d_in[6];
    const float* sp_offset  = (const float*)d_in[7];
    const float* norm_w     = (const float*)d_in[8];
    const float* q_w        = (const float*)d_in[9];
    const float* q_phase    = (const float*)d_in[10];
    const float* out_A      = (const float*)d_in[11];
    const float* out_B      = (const float*)d_in[12];
    const float* fc1_w      = (const float*)d_in[13];
    const float* fc2_w      = (const float*)d_in[14];
    const float* head_w     = (const float*)d_in[15];
    float* out = (float*)d_out;
    float* ws  = (float*)d_ws;

    setup_k<<<1, 64, 0, stream>>>(tok_A, tok_start, tok_stride, sp_amp, sp_phase,
                                  sp_slope, sp_offset, norm_w, q_w, q_phase, out_A, ws);
    micro_main<<<NBLK, NT, 0, stream>>>(idx, ws, out, norm_w, out_B, fc1_w, fc2_w, head_w);
}

// Round 7
// 37.430 us; speedup vs baseline: 1.8379x; 1.0571x over previous
//
#include <hip/hip_runtime.h>
#include <math.h>

#define T 34
#define V 14
#define NT 256
#define NBLK 2176
#define NWAVES 8704            // NBLK * 4 waves
#define LIM (65536 * 34)

typedef float f32x4 __attribute__((ext_vector_type(4)));

__global__ __launch_bounds__(NT, 4) void micro_fused(
    const int* __restrict__ idx, float* __restrict__ out,
    const float* __restrict__ p_tokA, const float* __restrict__ p_tokStart,
    const float* __restrict__ p_tokStride, const float* __restrict__ p_spAmp,
    const float* __restrict__ p_spPhase, const float* __restrict__ p_spSlope,
    const float* __restrict__ p_spOffset, const float* __restrict__ norm_w,
    const float* __restrict__ q_w, const float* __restrict__ q_phase,
    const float* __restrict__ out_A, const float* __restrict__ out_B,
    const float* __restrict__ fc1_w, const float* __restrict__ fc2_w,
    const float* __restrict__ head_w)
{
    __shared__ float G_lds[V * 35];      // 1960 B
    __shared__ float TE_lds[V * 2];      // 112 B
    __shared__ float POS_lds[T * 3];     // 408 B
    __shared__ float gbW[4][2][104];     // 3328 B
    __shared__ float stageAll[4 * 896];  // 14336 B; setup scratch then logit stage
    // total ~19.7 KB -> 8 blocks/CU LDS-limit

    const int tid = threadIdx.x;
    const int w = tid >> 6, lane = tid & 63;
    const int wid = blockIdx.x * 4 + w;

    float* sA = stageAll;            // A_pad[34][35] during setup
    float* sK = stageAll + 1200;     // K[34][5]
    float* sQ = stageAll + 1370;     // Q[34][5]

    // ---------- setup phase 1: TE, POS, K, Q (parallel) ----------
    if (tid < V) {
        float ang = p_tokStart[0] + (float)tid * p_tokStride[0];
        TE_lds[2 * tid]     = p_tokA[0] * cosf(ang);
        TE_lds[2 * tid + 1] = p_tokA[0] * sinf(ang);
    }
    if (tid < T) {
        float th = (float)tid * 0.62831853071795864769f + p_spPhase[0]; // 2*pi/10
        float p0 = p_spAmp[0] * cosf(th), p1 = p_spAmp[0] * sinf(th);
        float p2 = p_spSlope[0] * (float)tid + p_spOffset[0];
        POS_lds[3 * tid] = p0; POS_lds[3 * tid + 1] = p1; POS_lds[3 * tid + 2] = p2;
        float kk[5];
        #pragma unroll
        for (int i = 0; i < 5; ++i)
            kk[i] = p0 * q_w[3 * i] + p1 * q_w[3 * i + 1] + p2 * q_w[3 * i + 2];
        float cc = cosf(q_phase[0]), ss = sinf(q_phase[0]);
        #pragma unroll
        for (int i = 0; i < 5; ++i) sK[tid * 5 + i] = kk[i];
        sQ[tid * 5 + 0] = cc * kk[0] - ss * kk[1];
        sQ[tid * 5 + 1] = ss * kk[0] + cc * kk[1];
        sQ[tid * 5 + 2] = kk[2]; sQ[tid * 5 + 3] = kk[3]; sQ[tid * 5 + 4] = kk[4];
    }
    __syncthreads();

    // ---------- setup phase 2: raw scores (s<=t) + G table (parallel) ----------
    for (int e = tid; e < T * T; e += NT) {
        unsigned tt = (unsigned)e / (unsigned)T;
        unsigned s  = (unsigned)e - tt * T;
        if (s <= tt) {
            float d = 0.f;
            #pragma unroll
            for (int i = 0; i < 5; ++i) d += sQ[tt * 5 + i] * sK[s * 5 + i];
            sA[tt * 35 + s] = d * 0.44721359549995793928f;
        }
    }
    for (int e = tid; e < V * 35; e += NT) {
        int v = e / 35, s = e - v * 35;
        float g = 0.f;
        if (s < T) {
            float x0 = TE_lds[2*v], x1 = TE_lds[2*v+1];
            float x2 = POS_lds[3*s], x3 = POS_lds[3*s+1], x4 = POS_lds[3*s+2];
            float ms = (x0*x0 + x1*x1 + x2*x2 + x3*x3 + x4*x4) * 0.2f;
            float r = rsqrtf(ms + 1e-5f);
            g = (x0 * norm_w[0] * out_A[0] + x1 * norm_w[1] * out_A[1]
               + x2 * norm_w[2] * out_A[2] + x3 * norm_w[3] * out_A[3]
               + x4 * norm_w[4] * out_A[4]) * r;
        }
        G_lds[e] = g;
    }
    __syncthreads();

    // ---------- setup phase 3: row softmax, fully unrolled, register-resident ----------
    if (tid < T) {
        const int tt = tid;
        float vals[T];                       // static indexing only (no scratch)
        #pragma unroll
        for (int s = 0; s < T; ++s) vals[s] = sA[tt * 35 + s];
        float mx = -1e30f;
        #pragma unroll
        for (int s = 0; s < T; ++s) if (s <= tt) mx = fmaxf(mx, vals[s]);
        float sum = 0.f;
        #pragma unroll
        for (int s = 0; s < T; ++s) {
            float e2 = (s <= tt) ? expf(vals[s] - mx) : 0.f;
            vals[s] = e2;
            sum += e2;
        }
        float inv = 1.f / sum;
        #pragma unroll
        for (int s = 0; s < T; ++s) sA[tt * 35 + s] = vals[s] * inv;
        sA[tt * 35 + 34] = 0.f;
    }
    __syncthreads();

    // ---------- per-lane invariants ----------
    const int t = (wid * 64 + lane) % T;   // invariant across this wave's tiles
    float A[T];
    #pragma unroll
    for (int s = 0; s < T; ++s) A[s] = sA[t * 35 + s];
    const float ps0 = POS_lds[3*t], ps1 = POS_lds[3*t+1], ps2 = POS_lds[3*t+2];
    float te0[V], te1[V];
    #pragma unroll
    for (int v = 0; v < V; ++v) { te0[v] = TE_lds[2*v]; te1[v] = TE_lds[2*v+1]; }
    __syncthreads();   // last barrier: stageAll now reusable as logit stage

    // uniform weights: literal-indexed -> scalar loads / SGPRs
    const float nw0 = norm_w[0], nw1 = norm_w[1], nw2 = norm_w[2], nw3 = norm_w[3], nw4 = norm_w[4];
    const float oB0 = out_B[0], oB1 = out_B[1], oB2 = out_B[2], oB3 = out_B[3], oB4 = out_B[4];
    float w1[2][5], hw[2][5], w20[5], w21[5];
    #pragma unroll
    for (int j = 0; j < 2; ++j)
        #pragma unroll
        for (int d = 0; d < 5; ++d) { w1[j][d] = fc1_w[j*5+d]; hw[j][d] = head_w[j*5+d]; }
    #pragma unroll
    for (int d = 0; d < 5; ++d) { w20[d] = fc2_w[2*d]; w21[d] = fc2_w[2*d+1]; }

    // staging-lane invariants
    const int s_a = (lane < T) ? lane : lane - T;
    const int i2 = lane + 64;
    const int s_b = (i2 < 68) ? i2 - 34 : i2 - 68;
    const bool act2 = (i2 < 102);

    float* gbA = gbW[w][0];
    float* gbB = gbW[w][1];
    float* stg = stageAll + w * 896;
    float2* stg2 = reinterpret_cast<float2*>(stg);
    const f32x4* st4 = reinterpret_cast<const f32x4*>(stg);

    auto computeItem = [&](int tile, int rbase, int curtok, const float* gbT) {
        float acc0 = 0.f, acc1 = 0.f;
        const float2* gbp = reinterpret_cast<const float2*>(gbT + rbase);
        #pragma unroll
        for (int s = 0; s < 17; ++s) {
            float2 gg = gbp[s];
            acc0 = fmaf(A[2*s],   gg.x, acc0);
            acc1 = fmaf(A[2*s+1], gg.y, acc1);
        }
        float acc = acc0 + acc1;

        float2 te = *reinterpret_cast<const float2*>(&TE_lds[curtok * 2]);
        float x0 = te.x + acc * oB0;
        float x1 = te.y + acc * oB1;
        float x2 = ps0 + acc * oB2;
        float x3 = ps1 + acc * oB3;
        float x4 = ps2 + acc * oB4;

        float ms = (x0*x0 + x1*x1 + x2*x2 + x3*x3 + x4*x4) * 0.2f;
        float rr = rsqrtf(ms + 1e-5f);
        float h0 = x0*rr*nw0, h1 = x1*rr*nw1, h2 = x2*rr*nw2, h3 = x3*rr*nw3, h4 = x4*rr*nw4;
        float f0 = fmaxf(0.f, h0*w1[0][0] + h1*w1[0][1] + h2*w1[0][2] + h3*w1[0][3] + h4*w1[0][4]);
        float f1 = fmaxf(0.f, h0*w1[1][0] + h1*w1[1][1] + h2*w1[1][2] + h3*w1[1][3] + h4*w1[1][4]);
        x0 += f0*w20[0] + f1*w21[0];
        x1 += f0*w20[1] + f1*w21[1];
        x2 += f0*w20[2] + f1*w21[2];
        x3 += f0*w20[3] + f1*w21[3];
        x4 += f0*w20[4] + f1*w21[4];

        ms = (x0*x0 + x1*x1 + x2*x2 + x3*x3 + x4*x4) * 0.2f;
        rr = rsqrtf(ms + 1e-5f);
        h0 = x0*rr*nw0; h1 = x1*rr*nw1; h2 = x2*rr*nw2; h3 = x3*rr*nw3; h4 = x4*rr*nw4;
        float p0 = h0*hw[0][0] + h1*hw[0][1] + h2*hw[0][2] + h3*hw[0][3] + h4*hw[0][4];
        float p1 = h0*hw[1][0] + h1*hw[1][1] + h2*hw[1][2] + h3*hw[1][3] + h4*hw[1][4];

        #pragma unroll
        for (int j = 0; j < 7; ++j) {
            float2 o2;
            o2.x = p0 * te0[2*j]   + p1 * te1[2*j];
            o2.y = p0 * te0[2*j+1] + p1 * te1[2*j+1];
            stg2[lane * 7 + j] = o2;
        }
        // same-wave LDS ordering: reads below see the writes above
        f32x4* outp = reinterpret_cast<f32x4*>(out) + (size_t)tile * 224;
        __builtin_nontemporal_store(st4[lane],       outp + lane);
        __builtin_nontemporal_store(st4[lane + 64],  outp + lane + 64);
        __builtin_nontemporal_store(st4[lane + 128], outp + lane + 128);
        if (lane < 32)
            __builtin_nontemporal_store(st4[lane + 192], outp + lane + 192);
    };

    // ---- 4 tiles per wave, processed as 2 pairs (2-way ILP) ----
    int tileA = wid, tileB = wid + NWAVES;
    int b0A = (tileA * 64) / T, b0B = (tileB * 64) / T;
    int tk0A = idx[b0A * T + lane];
    int tk1A = idx[min(b0A * T + lane + 64, LIM - 1)];
    int tkoA = idx[tileA * 64 + lane];
    int tk0B = idx[b0B * T + lane];
    int tk1B = idx[min(b0B * T + lane + 64, LIM - 1)];
    int tkoB = idx[tileB * 64 + lane];

    #pragma unroll
    for (int it = 0; it < 2; ++it) {
        gbA[lane] = G_lds[tk0A * 35 + s_a];
        if (act2) gbA[i2] = G_lds[tk1A * 35 + s_b];
        gbB[lane] = G_lds[tk0B * 35 + s_a];
        if (act2) gbB[i2] = G_lds[tk1B * 35 + s_b];

        const int rbA = ((tileA * 64 + lane) / T - b0A) * T;
        const int rbB = ((tileB * 64 + lane) / T - b0B) * T;
        const int ctA = tkoA, ctB = tkoB;
        const int tA = tileA, tB = tileB;

        if (it == 0) {
            tileA += 2 * NWAVES; tileB += 2 * NWAVES;
            b0A = (tileA * 64) / T; b0B = (tileB * 64) / T;
            tk0A = idx[b0A * T + lane];
            tk1A = idx[min(b0A * T + lane + 64, LIM - 1)];
            tkoA = idx[tileA * 64 + lane];
            tk0B = idx[b0B * T + lane];
            tk1B = idx[min(b0B * T + lane + 64, LIM - 1)];
            tkoB = idx[tileB * 64 + lane];
        }

        computeItem(tA, rbA, ctA, gbA);
        computeItem(tB, rbB, ctB, gbB);
    }
}

extern "C" void kernel_launch(void* const* d_in, const int* in_sizes, int n_in,
                              void* d_out, int out_size, void* d_ws, size_t ws_size,
                              hipStream_t stream) {
    const int*   idx        = (const int*)  d_in[0];
    const float* tok_A      = (const float*)d_in[1];
    const float* tok_start  = (const float*)d_in[2];
    const float* tok_stride = (const float*)d_in[3];
    const float* sp_amp     = (const float*)d_in[4];
    const float* sp_phase   = (const float*)d_in[5];
    const float* sp_slope   = (const float*)d_in[6];
    const float* sp_offset  = (const float*)d_in[7];
    const float* norm_w     = (const float*)d_in[8];
    const float* q_w        = (const float*)d_in[9];
    const float* q_phase    = (const float*)d_in[10];
    const float* out_A      = (const float*)d_in[11];
    const float* out_B      = (const float*)d_in[12];
    const float* fc1_w      = (const float*)d_in[13];
    const float* fc2_w      = (const float*)d_in[14];
    const float* head_w     = (const float*)d_in[15];
    float* out = (float*)d_out;

    micro_fused<<<NBLK, NT, 0, stream>>>(idx, out, tok_A, tok_start, tok_stride,
                                         sp_amp, sp_phase, sp_slope, sp_offset,
                                         norm_w, q_w, q_phase, out_A, out_B,
                                         fc1_w, fc2_w, head_w);
}

// Round 8
// 35.943 us; speedup vs baseline: 1.9139x; 1.0414x over previous
//
#include <hip/hip_runtime.h>
#include <math.h>

#define T 34
#define V 14
#define NT 256
#define NBLK 1088
#define NWAVES 4352            // NBLK*4; 4352 = 17*256 -> tile stride preserves t-invariance
#define KTILES 8               // tiles per wave; NWAVES*KTILES*64 = 65536*34
#define NPAIRS 4
#define LIM (65536 * 34)

typedef float f32x4 __attribute__((ext_vector_type(4)));

__global__ __launch_bounds__(NT, 4) void micro_fused(
    const int* __restrict__ idx, float* __restrict__ out,
    const float* __restrict__ p_tokA, const float* __restrict__ p_tokStart,
    const float* __restrict__ p_tokStride, const float* __restrict__ p_spAmp,
    const float* __restrict__ p_spPhase, const float* __restrict__ p_spSlope,
    const float* __restrict__ p_spOffset, const float* __restrict__ norm_w,
    const float* __restrict__ q_w, const float* __restrict__ q_phase,
    const float* __restrict__ out_A, const float* __restrict__ out_B,
    const float* __restrict__ fc1_w, const float* __restrict__ fc2_w,
    const float* __restrict__ head_w)
{
    __shared__ float G_lds[V * 35];      // 1960 B
    __shared__ float TE_lds[V * 2];      // 112 B
    __shared__ float POS_lds[T * 3];     // 408 B
    __shared__ float gbW[4][2][104];     // 3328 B
    __shared__ float stageAll[4 * 896];  // 14336 B; setup scratch then logit stage
    // total ~19.7 KB -> 5 blocks/CU fit easily (LDS 94.6 KB at 5)

    const int tid = threadIdx.x;
    const int w = tid >> 6, lane = tid & 63;
    const int wid = blockIdx.x * 4 + w;

    float* sA = stageAll;            // raw scores A[34][35] during setup
    float* sK = stageAll + 1200;     // K[34][5]
    float* sQ = stageAll + 1370;     // Q[34][5]

    // ---------- setup phase 1: TE, POS, K, Q (parallel) ----------
    if (tid < V) {
        float ang = p_tokStart[0] + (float)tid * p_tokStride[0];
        TE_lds[2 * tid]     = p_tokA[0] * cosf(ang);
        TE_lds[2 * tid + 1] = p_tokA[0] * sinf(ang);
    }
    if (tid < T) {
        float th = (float)tid * 0.62831853071795864769f + p_spPhase[0]; // 2*pi/10
        float p0 = p_spAmp[0] * cosf(th), p1 = p_spAmp[0] * sinf(th);
        float p2 = p_spSlope[0] * (float)tid + p_spOffset[0];
        POS_lds[3 * tid] = p0; POS_lds[3 * tid + 1] = p1; POS_lds[3 * tid + 2] = p2;
        float kk[5];
        #pragma unroll
        for (int i = 0; i < 5; ++i)
            kk[i] = p0 * q_w[3 * i] + p1 * q_w[3 * i + 1] + p2 * q_w[3 * i + 2];
        float cc = cosf(q_phase[0]), ss = sinf(q_phase[0]);
        #pragma unroll
        for (int i = 0; i < 5; ++i) sK[tid * 5 + i] = kk[i];
        sQ[tid * 5 + 0] = cc * kk[0] - ss * kk[1];
        sQ[tid * 5 + 1] = ss * kk[0] + cc * kk[1];
        sQ[tid * 5 + 2] = kk[2]; sQ[tid * 5 + 3] = kk[3]; sQ[tid * 5 + 4] = kk[4];
    }
    __syncthreads();

    // ---------- setup phase 2: raw scores (all entries; 0 above diag) + G table ----------
    for (int e = tid; e < T * T; e += NT) {
        unsigned tt = (unsigned)e / (unsigned)T;
        unsigned s  = (unsigned)e - tt * T;
        float d = 0.f;
        #pragma unroll
        for (int i = 0; i < 5; ++i) d += sQ[tt * 5 + i] * sK[s * 5 + i];
        sA[tt * 35 + s] = (s <= tt) ? d * 0.44721359549995793928f : 0.f;
    }
    for (int e = tid; e < V * 35; e += NT) {
        int v = e / 35, s = e - v * 35;
        float g = 0.f;
        if (s < T) {
            float x0 = TE_lds[2*v], x1 = TE_lds[2*v+1];
            float x2 = POS_lds[3*s], x3 = POS_lds[3*s+1], x4 = POS_lds[3*s+2];
            float ms = (x0*x0 + x1*x1 + x2*x2 + x3*x3 + x4*x4) * 0.2f;
            float r = rsqrtf(ms + 1e-5f);
            g = (x0 * norm_w[0] * out_A[0] + x1 * norm_w[1] * out_A[1]
               + x2 * norm_w[2] * out_A[2] + x3 * norm_w[3] * out_A[3]
               + x4 * norm_w[4] * out_A[4]) * r;
        }
        G_lds[e] = g;
    }
    __syncthreads();

    // ---------- per-lane invariants: load raw score row, softmax in registers ----------
    const int t = (wid * 64 + lane) % T;   // invariant across this wave's tiles
    float A[T];
    #pragma unroll
    for (int s = 0; s < T; ++s) A[s] = sA[t * 35 + s];
    {
        float mx = -1e30f;
        #pragma unroll
        for (int s = 0; s < T; ++s) if (s <= t) mx = fmaxf(mx, A[s]);
        float sum = 0.f;
        #pragma unroll
        for (int s = 0; s < T; ++s) {
            float e2 = (s <= t) ? expf(A[s] - mx) : 0.f;
            A[s] = e2;
            sum += e2;
        }
        float inv = 1.f / sum;
        #pragma unroll
        for (int s = 0; s < T; ++s) A[s] *= inv;
    }
    const float ps0 = POS_lds[3*t], ps1 = POS_lds[3*t+1], ps2 = POS_lds[3*t+2];
    float te0[V], te1[V];
    #pragma unroll
    for (int v = 0; v < V; ++v) { te0[v] = TE_lds[2*v]; te1[v] = TE_lds[2*v+1]; }
    __syncthreads();   // last barrier: stageAll now reusable as logit stage

    // uniform weights: literal-indexed -> scalar loads / SGPRs
    const float nw0 = norm_w[0], nw1 = norm_w[1], nw2 = norm_w[2], nw3 = norm_w[3], nw4 = norm_w[4];
    const float oB0 = out_B[0], oB1 = out_B[1], oB2 = out_B[2], oB3 = out_B[3], oB4 = out_B[4];
    float w1[2][5], hw[2][5], w20[5], w21[5];
    #pragma unroll
    for (int j = 0; j < 2; ++j)
        #pragma unroll
        for (int d = 0; d < 5; ++d) { w1[j][d] = fc1_w[j*5+d]; hw[j][d] = head_w[j*5+d]; }
    #pragma unroll
    for (int d = 0; d < 5; ++d) { w20[d] = fc2_w[2*d]; w21[d] = fc2_w[2*d+1]; }

    // staging-lane invariants
    const int s_a = (lane < T) ? lane : lane - T;
    const int i2 = lane + 64;
    const int s_b = (i2 < 68) ? i2 - 34 : i2 - 68;
    const bool act2 = (i2 < 102);

    float* gbA = gbW[w][0];
    float* gbB = gbW[w][1];
    float* stg = stageAll + w * 896;
    float2* stg2 = reinterpret_cast<float2*>(stg);
    const f32x4* st4 = reinterpret_cast<const f32x4*>(stg);

    auto computeItem = [&](int tile, int rbase, int curtok, const float* gbT) {
        float acc0 = 0.f, acc1 = 0.f;
        const float2* gbp = reinterpret_cast<const float2*>(gbT + rbase);
        #pragma unroll
        for (int s = 0; s < 17; ++s) {
            float2 gg = gbp[s];
            acc0 = fmaf(A[2*s],   gg.x, acc0);
            acc1 = fmaf(A[2*s+1], gg.y, acc1);
        }
        float acc = acc0 + acc1;

        float2 te = *reinterpret_cast<const float2*>(&TE_lds[curtok * 2]);
        float x0 = te.x + acc * oB0;
        float x1 = te.y + acc * oB1;
        float x2 = ps0 + acc * oB2;
        float x3 = ps1 + acc * oB3;
        float x4 = ps2 + acc * oB4;

        float ms = (x0*x0 + x1*x1 + x2*x2 + x3*x3 + x4*x4) * 0.2f;
        float rr = rsqrtf(ms + 1e-5f);
        float h0 = x0*rr*nw0, h1 = x1*rr*nw1, h2 = x2*rr*nw2, h3 = x3*rr*nw3, h4 = x4*rr*nw4;
        float f0 = fmaxf(0.f, h0*w1[0][0] + h1*w1[0][1] + h2*w1[0][2] + h3*w1[0][3] + h4*w1[0][4]);
        float f1 = fmaxf(0.f, h0*w1[1][0] + h1*w1[1][1] + h2*w1[1][2] + h3*w1[1][3] + h4*w1[1][4]);
        x0 += f0*w20[0] + f1*w21[0];
        x1 += f0*w20[1] + f1*w21[1];
        x2 += f0*w20[2] + f1*w21[2];
        x3 += f0*w20[3] + f1*w21[3];
        x4 += f0*w20[4] + f1*w21[4];

        ms = (x0*x0 + x1*x1 + x2*x2 + x3*x3 + x4*x4) * 0.2f;
        rr = rsqrtf(ms + 1e-5f);
        h0 = x0*rr*nw0; h1 = x1*rr*nw1; h2 = x2*rr*nw2; h3 = x3*rr*nw3; h4 = x4*rr*nw4;
        float p0 = h0*hw[0][0] + h1*hw[0][1] + h2*hw[0][2] + h3*hw[0][3] + h4*hw[0][4];
        float p1 = h0*hw[1][0] + h1*hw[1][1] + h2*hw[1][2] + h3*hw[1][3] + h4*hw[1][4];

        #pragma unroll
        for (int j = 0; j < 7; ++j) {
            float2 o2;
            o2.x = p0 * te0[2*j]   + p1 * te1[2*j];
            o2.y = p0 * te0[2*j+1] + p1 * te1[2*j+1];
            stg2[lane * 7 + j] = o2;
        }
        // same-wave LDS ordering: reads below see the writes above
        f32x4* outp = reinterpret_cast<f32x4*>(out) + (size_t)tile * 224;
        __builtin_nontemporal_store(st4[lane],       outp + lane);
        __builtin_nontemporal_store(st4[lane + 64],  outp + lane + 64);
        __builtin_nontemporal_store(st4[lane + 128], outp + lane + 128);
        if (lane < 32)
            __builtin_nontemporal_store(st4[lane + 192], outp + lane + 192);
    };

    // ---- 8 tiles per wave, processed as 4 pairs (2-way ILP, cross-pair prefetch) ----
    int tileA = wid, tileB = wid + NWAVES;
    int b0A = (tileA * 64) / T, b0B = (tileB * 64) / T;
    int tk0A = idx[b0A * T + lane];
    int tk1A = idx[min(b0A * T + lane + 64, LIM - 1)];
    int tkoA = idx[tileA * 64 + lane];
    int tk0B = idx[b0B * T + lane];
    int tk1B = idx[min(b0B * T + lane + 64, LIM - 1)];
    int tkoB = idx[tileB * 64 + lane];

    #pragma unroll
    for (int it = 0; it < NPAIRS; ++it) {
        gbA[lane] = G_lds[tk0A * 35 + s_a];
        if (act2) gbA[i2] = G_lds[tk1A * 35 + s_b];
        gbB[lane] = G_lds[tk0B * 35 + s_a];
        if (act2) gbB[i2] = G_lds[tk1B * 35 + s_b];

        const int rbA = ((tileA * 64 + lane) / T - b0A) * T;
        const int rbB = ((tileB * 64 + lane) / T - b0B) * T;
        const int ctA = tkoA, ctB = tkoB;
        const int tA = tileA, tB = tileB;

        if (it < NPAIRS - 1) {
            tileA += 2 * NWAVES; tileB += 2 * NWAVES;
            b0A = (tileA * 64) / T; b0B = (tileB * 64) / T;
            tk0A = idx[b0A * T + lane];
            tk1A = idx[min(b0A * T + lane + 64, LIM - 1)];
            tkoA = idx[tileA * 64 + lane];
            tk0B = idx[b0B * T + lane];
            tk1B = idx[min(b0B * T + lane + 64, LIM - 1)];
            tkoB = idx[tileB * 64 + lane];
        }

        computeItem(tA, rbA, ctA, gbA);
        computeItem(tB, rbB, ctB, gbB);
    }
}

extern "C" void kernel_launch(void* const* d_in, const int* in_sizes, int n_in,
                              void* d_out, int out_size, void* d_ws, size_t ws_size,
                              hipStream_t stream) {
    const int*   idx        = (const int*)  d_in[0];
    const float* tok_A      = (const float*)d_in[1];
    const float* tok_start  = (const float*)d_in[2];
    const float* tok_stride = (const float*)d_in[3];
    const float* sp_amp     = (const float*)d_in[4];
    const float* sp_phase   = (const float*)d_in[5];
    const float* sp_slope   = (const float*)d_in[6];
    const float* sp_offset  = (const float*)d_in[7];
    const float* norm_w     = (const float*)d_in[8];
    const float* q_w        = (const float*)d_in[9];
    const float* q_phase    = (const float*)d_in[10];
    const float* out_A      = (const float*)d_in[11];
    const float* out_B      = (const float*)d_in[12];
    const float* fc1_w      = (const float*)d_in[13];
    const float* fc2_w      = (const float*)d_in[14];
    const float* head_w     = (const float*)d_in[15];
    float* out = (float*)d_out;

    micro_fused<<<NBLK, NT, 0, stream>>>(idx, out, tok_A, tok_start, tok_stride,
                                         sp_amp, sp_phase, sp_slope, sp_offset,
                                         norm_w, q_w, q_phase, out_A, out_B,
                                         fc1_w, fc2_w, head_w);
}